// Round 2
// 365.448 us; speedup vs baseline: 1.0224x; 1.0224x over previous
//
#include <hip/hip_runtime.h>

#define RAD   1
#define EPS_F 0.01f
#define LR_H  512
#define LR_W  512
#define HR_H  2048
#define HR_W  2048
#define NC    12   // N*C = 4*3

#define LR_PLANE (LR_H * LR_W)
#define HR_PLANE (HR_H * HR_W)
#define LR_TOTAL (NC * LR_PLANE)
#define HR_TOTAL (NC * HR_PLANE)

// ---- fused LR pass: stats -> A,b -> 3x3 box -> mA,mb, all in LDS ----
// One block = one 32x32 output tile. Halo x/y tile 36x36, A/b tile 34x34.
#define TILE 32
#define XT   (TILE + 4)   // 36
#define XSTR (XT + 1)     // 37 (odd stride: no bank conflicts)
#define AT   (TILE + 2)   // 34
#define ASTR (AT + 1)     // 35

__global__ void __launch_bounds__(256) k_fused_lr(
    const float* __restrict__ x, const float* __restrict__ y,
    float* __restrict__ mA, float* __restrict__ mb) {
    __shared__ float xs[XT * XSTR];
    __shared__ float ys[XT * XSTR];
    __shared__ float As[AT * ASTR];
    __shared__ float Bs[AT * ASTR];

    int bid = blockIdx.x;
    int p   = bid >> 8;          // plane (16x16 tiles per plane)
    int rem = bid & 255;
    int ty  = rem >> 4, tx = rem & 15;
    int oy  = ty * TILE, ox = tx * TILE;
    const float* xp = x + (size_t)p * LR_PLANE;
    const float* yp = y + (size_t)p * LR_PLANE;
    int tid = threadIdx.x;

    // Stage x,y halo tile (rows/cols oy-2..oy+33 clamped). xs[k] holds
    // x[clamp(oy+k-2)], so replicated edge rows are materialized.
    for (int i = tid; i < XT * XT; i += 256) {
        int r  = i / XT, c = i - r * XT;
        int gr = min(max(oy + r - 2, 0), LR_H - 1);
        int gc = min(max(ox + c - 2, 0), LR_W - 1);
        xs[r * XSTR + c] = xp[gr * LR_W + gc];
        ys[r * XSTR + c] = yp[gr * LR_W + gc];
    }
    __syncthreads();

    // A,b at the 34x34 CLAMPED positions q=clamp(oy+k-1), pc=clamp(ox+c-1).
    // Stats taps are x[clamp(q+d)][clamp(pc+e)]; map into xs via
    // lds_row = clamp(q+d) - oy + 2 (always in [0,35]).
    for (int i = tid; i < AT * AT; i += 256) {
        int k  = i / AT, c = i - k * AT;
        int q  = min(max(oy + k - 1, 0), LR_H - 1);
        int pc = min(max(ox + c - 1, 0), LR_W - 1);
        int rows[3] = { max(q - 1, 0)         - oy + 2,
                        q                     - oy + 2,
                        min(q + 1, LR_H - 1)  - oy + 2 };
        int cols[3] = { max(pc - 1, 0)        - ox + 2,
                        pc                    - ox + 2,
                        min(pc + 1, LR_W - 1) - ox + 2 };
        float sx = 0.f, sy = 0.f, sxy = 0.f, sxx = 0.f;
#pragma unroll
        for (int a = 0; a < 3; ++a) {
            int ro = rows[a] * XSTR;
#pragma unroll
            for (int b2 = 0; b2 < 3; ++b2) {
                float xv = xs[ro + cols[b2]];
                float yv = ys[ro + cols[b2]];
                sx  += xv;
                sy  += yv;
                sxy += xv * yv;
                sxx += xv * xv;
            }
        }
        const float inv9 = 1.0f / 9.0f;
        float mx  = sx * inv9;
        float my  = sy * inv9;
        float cov = sxy * inv9 - mx * my;
        float var = sxx * inv9 - mx * mx;
        float Av  = cov / (var + EPS_F);
        As[k * ASTR + c] = Av;
        Bs[k * ASTR + c] = my - Av * mx;
    }
    __syncthreads();

    // 3x3 box of A,b -> 32x32 outputs. As already holds edge-replicated
    // values, so taps are simply As[r+a][c+b].
    float* mAp = mA + (size_t)p * LR_PLANE;
    float* mbp = mb + (size_t)p * LR_PLANE;
    for (int i = tid; i < TILE * TILE; i += 256) {
        int r = i >> 5, c = i & 31;
        float sA = 0.f, sB = 0.f;
#pragma unroll
        for (int a = 0; a < 3; ++a) {
            int ro = (r + a) * ASTR + c;
#pragma unroll
            for (int b2 = 0; b2 < 3; ++b2) {
                sA += As[ro + b2];
                sB += Bs[ro + b2];
            }
        }
        const float inv9 = 1.0f / 9.0f;
        mAp[(size_t)(oy + r) * LR_W + (ox + c)] = sA * inv9;
        mbp[(size_t)(oy + r) * LR_W + (ox + c)] = sB * inv9;
    }
}

// K3 (unchanged): one block per (plane, HR row). Stage H-lerped LR rows of
// mA/mb in LDS, then per-pixel W-lerp + fused FMA/clip.
__global__ void __launch_bounds__(256) k_upsample_fuse(
    const float* __restrict__ mA, const float* __restrict__ mb,
    const float* __restrict__ xhr, float* __restrict__ out) {
    __shared__ float hA[513];
    __shared__ float hb[513];

    int bid = blockIdx.x;                 // plane * HR_H + i
    int i     = bid & (HR_H - 1);
    int plane = bid >> 11;

    const float scale = (float)(LR_H - 1) / (float)(HR_H - 1);

    float ph = i * scale;
    int   i0 = (int)ph;
    int   i1 = min(i0 + 1, LR_H - 1);
    float th = ph - (float)i0;
    float omh = 1.0f - th;

    const float* Ap = mA + (size_t)plane * LR_PLANE;
    const float* bp = mb + (size_t)plane * LR_PLANE;
    int tid = threadIdx.x;

    for (int c = tid; c < 513; c += 256) {
        int col = min(c, LR_W - 1);
        float a0 = Ap[i0 * LR_W + col];
        float a1 = Ap[i1 * LR_W + col];
        float b0 = bp[i0 * LR_W + col];
        float b1 = bp[i1 * LR_W + col];
        hA[c] = a0 * omh + a1 * th;
        hb[c] = b0 * omh + b1 * th;
    }
    __syncthreads();

    const float* xrow = xhr + (size_t)plane * HR_PLANE + (size_t)i * HR_W;
    float*       orow = out + (size_t)plane * HR_PLANE + (size_t)i * HR_W;

#pragma unroll
    for (int g = 0; g < 2; ++g) {
        int j = (tid + g * 256) * 4;
        const float4 xv = *(const float4*)(xrow + j);
        float xin[4] = {xv.x, xv.y, xv.z, xv.w};
        float r[4];
#pragma unroll
        for (int k = 0; k < 4; ++k) {
            float pw = (float)(j + k) * scale;
            int   j0 = (int)pw;
            float tw = pw - (float)j0;
            float omw = 1.0f - tw;
            float a  = hA[j0] * omw + hA[j0 + 1] * tw;
            float bb = hb[j0] * omw + hb[j0 + 1] * tw;
            float v  = a * xin[k] + bb;
            r[k] = fminf(fmaxf(v, 0.0f), 255.0f);
        }
        float4 o;
        o.x = r[0]; o.y = r[1]; o.z = r[2]; o.w = r[3];
        *(float4*)(orow + j) = o;
    }
}

extern "C" void kernel_launch(void* const* d_in, const int* in_sizes, int n_in,
                              void* d_out, int out_size, void* d_ws, size_t ws_size,
                              hipStream_t stream) {
    const float* x_lr = (const float*)d_in[0];
    const float* y_lr = (const float*)d_in[1];
    const float* x_hr = (const float*)d_in[2];
    float* out = (float*)d_out;

    float* mA = (float*)d_ws;
    float* mb = mA + LR_TOTAL;

    {
        int threads = 256;
        int blocks = NC * 16 * 16;         // one block per 32x32 LR tile
        k_fused_lr<<<blocks, threads, 0, stream>>>(x_lr, y_lr, mA, mb);
    }
    {
        int threads = 256;
        int blocks = NC * HR_H;            // one block per HR row per plane
        k_upsample_fuse<<<blocks, threads, 0, stream>>>(mA, mb, x_hr, out);
    }
}